// Round 2
// baseline (1950.107 us; speedup 1.0000x reference)
//
#include <hip/hip_runtime.h>
#include <hip/hip_bf16.h>

#define D        256
#define D4       64          // D/4 float4s per row
#define TM       32          // rows per block
#define KC       32          // codes staged per chunk
#define ZSTRIDE  260         // padded row stride in floats (16B-aligned, bank-spread)
#define NT       256

// ||c_k||^2 in f64, one 64-lane block per code
__global__ __launch_bounds__(64) void vq_cnorm(const float* __restrict__ cb,
                                               double* __restrict__ cn2) {
  const int k    = blockIdx.x;
  const int lane = threadIdx.x;
  const float4 v = ((const float4*)(cb + (size_t)k * D))[lane];
  double s = (double)v.x * v.x + (double)v.y * v.y +
             (double)v.z * v.z + (double)v.w * v.w;
  for (int off = 32; off; off >>= 1) s += __shfl_down(s, off, 64);
  if (lane == 0) cn2[k] = s;
}

__global__ __launch_bounds__(NT) void vq_main(const float* __restrict__ z,
                                              const float* __restrict__ cb,
                                              const double* __restrict__ cn2,
                                              float* __restrict__ zq_out,
                                              float* __restrict__ idx_out,
                                              double* __restrict__ loss_acc,
                                              int K) {
  __shared__ float zs[TM * ZSTRIDE];   // 33.3 KB
  __shared__ float cs[KC * ZSTRIDE];   // 33.3 KB
  __shared__ int   idx_sm[TM];

  const int t = threadIdx.x;
  const size_t rowbase = (size_t)blockIdx.x * TM;

  // stage z tile (coalesced float4 loads, padded LDS rows)
  {
    const float4* zg = (const float4*)(z + rowbase * D);
    for (int i = t; i < TM * D4; i += NT) {
      const int r = i >> 6, c = i & 63;
      *(float4*)&zs[r * ZSTRIDE + c * 4] = zg[i];
    }
  }

  const int g  = t >> 4;              // 0..15 -> row pair
  const int j  = t & 15;              // 0..15 -> code pair (j, j+16)
  const int r0 = g * 2, r1 = g * 2 + 1;

  double best0 = 1e300, best1 = 1e300;
  int    bi0 = 0, bi1 = 0;

  for (int kb = 0; kb < K; kb += KC) {
    __syncthreads();                   // protect cs from previous iteration
    {
      const float4* cg = (const float4*)(cb + (size_t)kb * D);
      for (int i = t; i < KC * D4; i += NT) {
        const int r = i >> 6, c = i & 63;
        *(float4*)&cs[r * ZSTRIDE + c * 4] = cg[i];
      }
    }
    __syncthreads();

    const float* zr0 = &zs[r0 * ZSTRIDE];
    const float* zr1 = &zs[r1 * ZSTRIDE];
    const float* ck0 = &cs[j * ZSTRIDE];
    const float* ck1 = &cs[(j + 16) * ZSTRIDE];

    double a00 = 0.0, a01 = 0.0, a10 = 0.0, a11 = 0.0;
    #pragma unroll 4
    for (int d0 = 0; d0 < D; d0 += 4) {
      const float4 za = *(const float4*)&zr0[d0];
      const float4 zb = *(const float4*)&zr1[d0];
      const float4 ca = *(const float4*)&ck0[d0];
      const float4 cc = *(const float4*)&ck1[d0];
      a00 = fma((double)za.x, (double)ca.x, a00);
      a00 = fma((double)za.y, (double)ca.y, a00);
      a00 = fma((double)za.z, (double)ca.z, a00);
      a00 = fma((double)za.w, (double)ca.w, a00);
      a01 = fma((double)za.x, (double)cc.x, a01);
      a01 = fma((double)za.y, (double)cc.y, a01);
      a01 = fma((double)za.z, (double)cc.z, a01);
      a01 = fma((double)za.w, (double)cc.w, a01);
      a10 = fma((double)zb.x, (double)ca.x, a10);
      a10 = fma((double)zb.y, (double)ca.y, a10);
      a10 = fma((double)zb.z, (double)ca.z, a10);
      a10 = fma((double)zb.w, (double)ca.w, a10);
      a11 = fma((double)zb.x, (double)cc.x, a11);
      a11 = fma((double)zb.y, (double)cc.y, a11);
      a11 = fma((double)zb.z, (double)cc.z, a11);
      a11 = fma((double)zb.w, (double)cc.w, a11);
    }

    const double cn0 = cn2[kb + j];
    const double cn1 = cn2[kb + j + 16];
    double dd;
    dd = cn0 - 2.0 * a00; if (dd < best0) { best0 = dd; bi0 = kb + j; }
    dd = cn1 - 2.0 * a01; if (dd < best0) { best0 = dd; bi0 = kb + j + 16; }
    dd = cn0 - 2.0 * a10; if (dd < best1) { best1 = dd; bi1 = kb + j; }
    dd = cn1 - 2.0 * a11; if (dd < best1) { best1 = dd; bi1 = kb + j + 16; }
  }

  // reduce (dist, idx) over the 16 lanes sharing each row pair;
  // np.argmin semantics: on equal dist keep the smaller index.
  for (int off = 8; off; off >>= 1) {
    double ob = __shfl_xor(best0, off, 16);
    int    oi = __shfl_xor(bi0,  off, 16);
    if (ob < best0 || (ob == best0 && oi < bi0)) { best0 = ob; bi0 = oi; }
    ob = __shfl_xor(best1, off, 16);
    oi = __shfl_xor(bi1,  off, 16);
    if (ob < best1 || (ob == best1 && oi < bi1)) { best1 = ob; bi1 = oi; }
  }
  if (j == 0) {
    idx_sm[r0] = bi0;
    idx_sm[r1] = bi1;
    idx_out[rowbase + r0] = (float)bi0;
    idx_out[rowbase + r1] = (float)bi1;
  }
  __syncthreads();

  // gather z_q rows, write z_q_st, accumulate loss in f64
  double ls = 0.0;
  const float4* cb4 = (const float4*)cb;
  float4* zq4 = (float4*)(zq_out + rowbase * D);
  for (int i = t; i < TM * D4; i += NT) {
    const int r = i >> 6, c = i & 63;
    const int k = idx_sm[r];
    const float4 q  = cb4[(size_t)k * D4 + c];
    const float4 zz = *(const float4*)&zs[r * ZSTRIDE + c * 4];
    zq4[i] = q;
    const double dx = (double)q.x - (double)zz.x;
    const double dy = (double)q.y - (double)zz.y;
    const double dz = (double)q.z - (double)zz.z;
    const double dw = (double)q.w - (double)zz.w;
    ls += dx * dx + dy * dy + dz * dz + dw * dw;
  }
  for (int off = 32; off; off >>= 1) ls += __shfl_down(ls, off, 64);
  if ((t & 63) == 0) atomicAdd(loss_acc, ls);
}

__global__ void vq_finalize(const double* __restrict__ loss_acc,
                            float* __restrict__ out, double inv) {
  const float l = (float)(loss_acc[0] * inv);
  out[0] = l;   // loss_vq
  out[1] = l;   // loss_commit (numerically identical)
}

extern "C" void kernel_launch(void* const* d_in, const int* in_sizes, int n_in,
                              void* d_out, int out_size, void* d_ws, size_t ws_size,
                              hipStream_t stream) {
  const float* z  = (const float*)d_in[0];
  const float* cb = (const float*)d_in[1];
  const int N = in_sizes[0] / D;     // 100352
  const int K = in_sizes[1] / D;     // 1024

  float* out     = (float*)d_out;
  float* zq_out  = out + 2;
  float* idx_out = out + 2 + (size_t)N * D;

  double* loss_acc = (double*)d_ws;
  double* cn2      = (double*)((char*)d_ws + 64);

  hipMemsetAsync(d_ws, 0, 64, stream);
  vq_cnorm<<<K, 64, 0, stream>>>(cb, cn2);
  vq_main<<<N / TM, NT, 0, stream>>>(z, cb, cn2, zq_out, idx_out, loss_acc, K);
  vq_finalize<<<1, 1, 0, stream>>>(loss_acc, out, 1.0 / ((double)N * (double)D));
}

// Round 7
// 808.443 us; speedup vs baseline: 2.4122x; 2.4122x over previous
//
#include <hip/hip_runtime.h>
#include <hip/hip_bf16.h>

typedef float  f32x4  __attribute__((ext_vector_type(4)));
typedef short  short4v __attribute__((ext_vector_type(4)));
typedef short  short8v __attribute__((ext_vector_type(8)));

#define DIM   256
#define BM    128
#define BN    128
#define NTM   256
#define EPS   0.05f
#define RB    2048
#define GB    1024

__device__ __forceinline__ ushort bf16rn(float f) {
  union { float f; uint u; } x; x.f = f;
  const uint u = x.u;
  return (ushort)((u + 0x7fffu + ((u >> 16) & 1u)) >> 16);
}
__device__ __forceinline__ float bf16tof(ushort h) {
  union { uint u; float f; } x; x.u = ((uint)h) << 16; return x.f;
}

// ||c_k||^2 in f64 (+ f32 copy), one 64-lane block per code
__global__ __launch_bounds__(64) void vq_cnorm(const float* __restrict__ cb,
                                               double* __restrict__ cn2,
                                               float* __restrict__ cnf) {
  const int k    = blockIdx.x;
  const int lane = threadIdx.x;
  const f32x4 v = ((const f32x4*)(cb + (size_t)k * DIM))[lane];
  double s = (double)v[0]*v[0] + (double)v[1]*v[1] +
             (double)v[2]*v[2] + (double)v[3]*v[3];
  for (int off = 32; off; off >>= 1) s += __shfl_down(s, off, 64);
  if (lane == 0) { cn2[k] = s; cnf[k] = (float)s; }
}

// Main: bf16-split MFMA distance pass + margin-based accept
__global__ __launch_bounds__(NTM, 2) void vq_mfma(const float* __restrict__ z,
                                                  const float* __restrict__ cb,
                                                  const float* __restrict__ cnf,
                                                  float* __restrict__ idx_out) {
  __shared__ __align__(16) ushort zhS[BM*64];
  __shared__ __align__(16) ushort zlS[BM*64];
  __shared__ __align__(16) ushort chS[BN*64];
  __shared__ __align__(16) ushort clS[BN*64];
  __shared__ float cns[1024];
  __shared__ float rb1[2][BM];
  __shared__ float rb2[2][BM];
  __shared__ int   ri1[2][BM];

  char* zhB = (char*)zhS; char* zlB = (char*)zlS;
  char* chB = (char*)chS; char* clB = (char*)clS;

  const int t  = threadIdx.x;
  const int l  = t & 63, w = t >> 6;
  const int wm = w >> 1, wn = w & 1;
  const int lr = l & 15, lg = l >> 4;
  const size_t rbase = (size_t)blockIdx.x * BM;
  const uint rswz = (uint)(lr & 7) << 4;

  for (int i = t; i < 1024; i += NTM) cns[i] = cnf[i];

  float b1[16], b2[16]; int i1[16];
  #pragma unroll
  for (int s = 0; s < 16; ++s) { b1[s] = 3.0e38f; b2[s] = 3.0e38f; i1[s] = 0; }

  const int kq = t & 15, r2 = t >> 4;
  const f32x4* zg4 = (const f32x4*)z;
  const f32x4* cg4 = (const f32x4*)cb;

  for (int chunk = 0; chunk < 8; ++chunk) {
    f32x4 acc[4][4];
    #pragma unroll
    for (int m = 0; m < 4; ++m)
      #pragma unroll
      for (int n = 0; n < 4; ++n) acc[m][n] = (f32x4){0.f, 0.f, 0.f, 0.f};

    for (int kt = 0; kt < 4; ++kt) {
      __syncthreads();
      // stage z-slice [128][64] and c-slice [128][64] as bf16 hi/lo, swizzled
      #pragma unroll
      for (int j = 0; j < 8; ++j) {
        const int r = r2 + j*16;
        const f32x4 vz = zg4[(rbase + r)*64 + kt*16 + kq];
        const f32x4 vc = cg4[((size_t)(chunk*BN + r))*64 + kt*16 + kq];
        short4v hz, lz, hc, lc;
        #pragma unroll
        for (int e = 0; e < 4; ++e) {
          const float fz = vz[e];
          const ushort hb = bf16rn(fz);
          hz[e] = (short)hb;
          lz[e] = (short)bf16rn(fz - bf16tof(hb));
          const float fc = vc[e];
          const ushort hb2 = bf16rn(fc);
          hc[e] = (short)hb2;
          lc[e] = (short)bf16rn(fc - bf16tof(hb2));
        }
        const uint off = ((uint)(r*128 + kq*8)) ^ ((uint)(r & 7) << 4);
        *(short4v*)(zhB + off) = hz;
        *(short4v*)(zlB + off) = lz;
        *(short4v*)(chB + off) = hc;
        *(short4v*)(clB + off) = lc;
      }
      __syncthreads();
      #pragma unroll
      for (int kk = 0; kk < 2; ++kk) {
        short8v ah[4], al_[4], bh[4], bl_[4];
        #pragma unroll
        for (int m = 0; m < 4; ++m) {
          const int r = wm*64 + m*16 + lr;
          const uint off = ((uint)(r*128 + kk*64 + lg*16)) ^ rswz;
          ah[m]  = *(const short8v*)(zhB + off);
          al_[m] = *(const short8v*)(zlB + off);
        }
        #pragma unroll
        for (int n = 0; n < 4; ++n) {
          const int r = wn*64 + n*16 + lr;
          const uint off = ((uint)(r*128 + kk*64 + lg*16)) ^ rswz;
          bh[n]  = *(const short8v*)(chB + off);
          bl_[n] = *(const short8v*)(clB + off);
        }
        #pragma unroll
        for (int m = 0; m < 4; ++m)
          #pragma unroll
          for (int n = 0; n < 4; ++n) {
            acc[m][n] = __builtin_amdgcn_mfma_f32_16x16x32_bf16(ah[m],  bh[n],  acc[m][n], 0, 0, 0);
            acc[m][n] = __builtin_amdgcn_mfma_f32_16x16x32_bf16(ah[m],  bl_[n], acc[m][n], 0, 0, 0);
            acc[m][n] = __builtin_amdgcn_mfma_f32_16x16x32_bf16(al_[m], bh[n],  acc[m][n], 0, 0, 0);
          }
      }
    }
    // epilogue: dd = ||c||^2 - 2 dot ; update best/second (codes ascend)
    #pragma unroll
    for (int m = 0; m < 4; ++m)
      #pragma unroll
      for (int n = 0; n < 4; ++n) {
        const int cg = chunk*128 + wn*64 + n*16 + lr;
        const float cn = cns[cg & 1023];
        #pragma unroll
        for (int r = 0; r < 4; ++r) {
          const float dd = fmaf(-2.0f, acc[m][n][r], cn);
          const int s = m*4 + r;
          const bool lt = dd < b1[s];
          b2[s] = lt ? b1[s] : fminf(b2[s], dd);
          i1[s] = lt ? cg : i1[s];
          b1[s] = lt ? dd : b1[s];
        }
      }
  }

  // merge across the 16 lanes sharing the same row set (same lg)
  #pragma unroll
  for (int s = 0; s < 16; ++s) {
    #pragma unroll
    for (int off = 1; off < 16; off <<= 1) {
      const float ob1 = __shfl_xor(b1[s], off, 16);
      const float ob2 = __shfl_xor(b2[s], off, 16);
      const int   oi  = __shfl_xor(i1[s], off, 16);
      const float hi  = fmaxf(b1[s], ob1);
      b2[s] = fminf(fminf(b2[s], ob2), hi);
      if (ob1 < b1[s] || (ob1 == b1[s] && oi < i1[s])) { b1[s] = ob1; i1[s] = oi; }
    }
  }
  if (lr == 0) {
    #pragma unroll
    for (int m = 0; m < 4; ++m)
      #pragma unroll
      for (int r = 0; r < 4; ++r) {
        const int s = m*4 + r;
        const int row = wm*64 + m*16 + lg*4 + r;
        rb1[wn][row] = b1[s]; rb2[wn][row] = b2[s]; ri1[wn][row] = i1[s];
      }
  }
  __syncthreads();
  if (t < BM) {
    const float a1 = rb1[0][t], a2 = rb2[0][t]; const int ai = ri1[0][t];
    const float c1 = rb1[1][t], c2 = rb2[1][t]; const int ci = ri1[1][t];
    const float m2 = fminf(fminf(a2, c2), fmaxf(a1, c1));
    float m1; int mi;
    if (c1 < a1 || (c1 == a1 && ci < ai)) { m1 = c1; mi = ci; } else { m1 = a1; mi = ai; }
    idx_out[rbase + t] = (m2 - m1 > EPS) ? (float)mi : -1.0f;
  }
}

// Exact f64 re-check for sentinel rows (matches round-1 exact semantics)
__global__ __launch_bounds__(256) void vq_recheck(const float* __restrict__ z,
                                                  const float* __restrict__ cb,
                                                  const double* __restrict__ cn2,
                                                  float* __restrict__ idx_out, int N) {
  __shared__ __align__(16) float zrow[DIM];
  __shared__ __align__(16) float cbs[32*DIM];
  __shared__ double bls[32];
  __shared__ int    bis[32];
  const int t = threadIdx.x;
  for (int row = blockIdx.x; row < N; row += RB) {
    const float f = idx_out[row];
    if (f >= 0.0f) continue;
    if (t < 64) ((f32x4*)zrow)[t] = ((const f32x4*)z)[(size_t)row*64 + t];
    double best = 1.0e300; int bidx = 0;
    for (int ch = 0; ch < 32; ++ch) {
      __syncthreads();
      #pragma unroll
      for (int i = 0; i < 8; ++i)
        ((f32x4*)cbs)[t + i*256] = ((const f32x4*)cb)[(size_t)ch*2048 + t + i*256];
      __syncthreads();
      const float* cr = cbs  + (t >> 3)*DIM + (t & 7)*32;
      const float* zr = zrow + (t & 7)*32;
      double s = 0.0;
      #pragma unroll
      for (int d = 0; d < 32; ++d) s = fma((double)zr[d], (double)cr[d], s);
      s += __shfl_xor(s, 4, 8);
      s += __shfl_xor(s, 2, 8);
      s += __shfl_xor(s, 1, 8);
      if ((t & 7) == 0) {
        const int code = ch*32 + (t >> 3);
        const double dd = cn2[code] - 2.0*s;
        if (dd < best) { best = dd; bidx = code; }
      }
    }
    __syncthreads();
    if ((t & 7) == 0) { bls[t >> 3] = best; bis[t >> 3] = bidx; }
    __syncthreads();
    if (t == 0) {
      double bb = bls[0]; int ii = bis[0];
      for (int q = 1; q < 32; ++q)
        if (bls[q] < bb || (bls[q] == bb && bis[q] < ii)) { bb = bls[q]; ii = bis[q]; }
      idx_out[row] = (float)ii;
    }
    __syncthreads();
  }
}

// Gather z_q, write z_q_st, accumulate loss (f64)
__global__ __launch_bounds__(256) void vq_gather(const float* __restrict__ z,
                                                 const float* __restrict__ cb,
                                                 const float* __restrict__ idxf,
                                                 float* __restrict__ zq,
                                                 double* __restrict__ loss_acc, int N) {
  const int t = threadIdx.x, wid = t >> 6, lane = t & 63;
  double ls = 0.0;
  for (int row = blockIdx.x*4 + wid; row < N; row += GB*4) {
    const int idx = (int)idxf[row];
    const f32x4 q  = ((const f32x4*)cb)[(size_t)idx*64 + lane];
    const f32x4 zz = ((const f32x4*)z)[(size_t)row*64 + lane];
    ((f32x4*)zq)[(size_t)row*64 + lane] = q;
    const double dx = (double)q[0] - (double)zz[0];
    const double dy = (double)q[1] - (double)zz[1];
    const double dz2 = (double)q[2] - (double)zz[2];
    const double dw = (double)q[3] - (double)zz[3];
    ls += dx*dx + dy*dy + dz2*dz2 + dw*dw;
  }
  #pragma unroll
  for (int off = 32; off; off >>= 1) ls += __shfl_down(ls, off, 64);
  __shared__ double wsum[4];
  if (lane == 0) wsum[wid] = ls;
  __syncthreads();
  if (t == 0) atomicAdd(loss_acc, wsum[0] + wsum[1] + wsum[2] + wsum[3]);
}

__global__ void vq_finalize(const double* __restrict__ loss_acc,
                            float* __restrict__ out, double inv) {
  const float l = (float)(loss_acc[0] * inv);
  out[0] = l;
  out[1] = l;
}

extern "C" void kernel_launch(void* const* d_in, const int* in_sizes, int n_in,
                              void* d_out, int out_size, void* d_ws, size_t ws_size,
                              hipStream_t stream) {
  const float* z  = (const float*)d_in[0];
  const float* cb = (const float*)d_in[1];
  const int N = in_sizes[0] / DIM;   // 100352
  const int K = in_sizes[1] / DIM;   // 1024
  (void)K;

  float* out     = (float*)d_out;
  float* zq_out  = out + 2;
  float* idx_out = out + 2 + (size_t)N * DIM;

  double* loss_acc = (double*)d_ws;
  double* cn2      = (double*)((char*)d_ws + 64);
  float*  cnf      = (float*)((char*)d_ws + 64 + 8192);

  hipMemsetAsync(d_ws, 0, 64, stream);
  vq_cnorm<<<1024, 64, 0, stream>>>(cb, cn2, cnf);
  vq_mfma<<<N / BM, NTM, 0, stream>>>(z, cb, cnf, idx_out);
  vq_recheck<<<RB, 256, 0, stream>>>(z, cb, cn2, idx_out, N);
  vq_gather<<<GB, 256, 0, stream>>>(z, cb, idx_out, zq_out, loss_acc, N);
  vq_finalize<<<1, 1, 0, stream>>>(loss_acc, out, 1.0 / ((double)N * (double)DIM));
}